// Round 1
// baseline (239.693 us; speedup 1.0000x reference)
//
#include <hip/hip_runtime.h>

// input_tensor: (32, 64, 64, 64) fp32  -- d_in[0]
// pool_input:   (32, 128, 128, 64) fp32 -- d_in[1]
// out:          (32, 128, 128, 64) fp32
// POOL == STRIDES == (2,2): non-overlapping windows ->
//   out[b,h,w,c] = (pool[b,h,w,c] == window max) ? input[b,h/2,w/2,c] : 0
//
// R2: 4 windows per thread (batch split into quarters b, b+8, b+16, b+24),
// 20 independent nontemporal loads issued up front (2x MLP vs R1's 10),
// 16 nontemporal stores. Pure streaming; every global byte touched exactly
// once (302 MB total -> ~46 us floor at 6.5 TB/s).

#define BB 32
#define HH 128
#define WW 128
#define CC 64
#define HO 64
#define WO 64
#define C4 (CC / 4)               // 16 float4 per (b,h,w)
#define WC4 (WW * C4)             // 2048 float4 per pool row
#define QN (8 * HO * WO * C4)     // 524,288 threads (bb = 0..7)
#define POOL_Q (8 * HH * WW * C4) // float4 offset between bb and bb+8 in pool

typedef float v4 __attribute__((ext_vector_type(4)));

__device__ __forceinline__ v4 vmax4(v4 a, v4 b) {
    v4 r;
    r.x = fmaxf(a.x, b.x); r.y = fmaxf(a.y, b.y);
    r.z = fmaxf(a.z, b.z); r.w = fmaxf(a.w, b.w);
    return r;
}

__device__ __forceinline__ v4 vsel(v4 p, v4 m, v4 v) {
    v4 r;
    r.x = (p.x == m.x) ? v.x : 0.0f;
    r.y = (p.y == m.y) ? v.y : 0.0f;
    r.z = (p.z == m.z) ? v.z : 0.0f;
    r.w = (p.w == m.w) ? v.w : 0.0f;
    return r;
}

__global__ __launch_bounds__(256) void unpool2d_kernel(
    const v4* __restrict__ input,  // (B,HO,WO,C4)
    const v4* __restrict__ pool,   // (B,H,W,C4)
    v4* __restrict__ out)          // (B,H,W,C4)
{
    const int t = blockIdx.x * blockDim.x + threadIdx.x;   // [0, QN)
    // decode (bb<8, i, j, c4), c4 fastest
    const int c4 = t & (C4 - 1);
    const int j  = (t >> 4) & (WO - 1);
    const int i  = (t >> 10) & (HO - 1);
    const int bb = t >> 16;                                 // 0..7

    const int base0 = ((bb * HH + 2 * i) * WW + 2 * j) * C4 + c4;
    const int base1 = base0 + POOL_Q;                       // bb+8
    const int base2 = base0 + 2 * POOL_Q;                   // bb+16
    const int base3 = base0 + 3 * POOL_Q;                   // bb+24

    // 20 independent loads, all issued before any use.
    const v4 p0_00 = __builtin_nontemporal_load(&pool[base0]);
    const v4 p0_01 = __builtin_nontemporal_load(&pool[base0 + C4]);
    const v4 p0_10 = __builtin_nontemporal_load(&pool[base0 + WC4]);
    const v4 p0_11 = __builtin_nontemporal_load(&pool[base0 + WC4 + C4]);
    const v4 p1_00 = __builtin_nontemporal_load(&pool[base1]);
    const v4 p1_01 = __builtin_nontemporal_load(&pool[base1 + C4]);
    const v4 p1_10 = __builtin_nontemporal_load(&pool[base1 + WC4]);
    const v4 p1_11 = __builtin_nontemporal_load(&pool[base1 + WC4 + C4]);
    const v4 p2_00 = __builtin_nontemporal_load(&pool[base2]);
    const v4 p2_01 = __builtin_nontemporal_load(&pool[base2 + C4]);
    const v4 p2_10 = __builtin_nontemporal_load(&pool[base2 + WC4]);
    const v4 p2_11 = __builtin_nontemporal_load(&pool[base2 + WC4 + C4]);
    const v4 p3_00 = __builtin_nontemporal_load(&pool[base3]);
    const v4 p3_01 = __builtin_nontemporal_load(&pool[base3 + C4]);
    const v4 p3_10 = __builtin_nontemporal_load(&pool[base3 + WC4]);
    const v4 p3_11 = __builtin_nontemporal_load(&pool[base3 + WC4 + C4]);
    const v4 vA = __builtin_nontemporal_load(&input[t]);
    const v4 vB = __builtin_nontemporal_load(&input[t + QN]);
    const v4 vC = __builtin_nontemporal_load(&input[t + 2 * QN]);
    const v4 vD = __builtin_nontemporal_load(&input[t + 3 * QN]);

    const v4 mA = vmax4(vmax4(p0_00, p0_01), vmax4(p0_10, p0_11));
    const v4 mB = vmax4(vmax4(p1_00, p1_01), vmax4(p1_10, p1_11));
    const v4 mC = vmax4(vmax4(p2_00, p2_01), vmax4(p2_10, p2_11));
    const v4 mD = vmax4(vmax4(p3_00, p3_01), vmax4(p3_10, p3_11));

    __builtin_nontemporal_store(vsel(p0_00, mA, vA), &out[base0]);
    __builtin_nontemporal_store(vsel(p0_01, mA, vA), &out[base0 + C4]);
    __builtin_nontemporal_store(vsel(p0_10, mA, vA), &out[base0 + WC4]);
    __builtin_nontemporal_store(vsel(p0_11, mA, vA), &out[base0 + WC4 + C4]);
    __builtin_nontemporal_store(vsel(p1_00, mB, vB), &out[base1]);
    __builtin_nontemporal_store(vsel(p1_01, mB, vB), &out[base1 + C4]);
    __builtin_nontemporal_store(vsel(p1_10, mB, vB), &out[base1 + WC4]);
    __builtin_nontemporal_store(vsel(p1_11, mB, vB), &out[base1 + WC4 + C4]);
    __builtin_nontemporal_store(vsel(p2_00, mC, vC), &out[base2]);
    __builtin_nontemporal_store(vsel(p2_01, mC, vC), &out[base2 + C4]);
    __builtin_nontemporal_store(vsel(p2_10, mC, vC), &out[base2 + WC4]);
    __builtin_nontemporal_store(vsel(p2_11, mC, vC), &out[base2 + WC4 + C4]);
    __builtin_nontemporal_store(vsel(p3_00, mD, vD), &out[base3]);
    __builtin_nontemporal_store(vsel(p3_01, mD, vD), &out[base3 + C4]);
    __builtin_nontemporal_store(vsel(p3_10, mD, vD), &out[base3 + WC4]);
    __builtin_nontemporal_store(vsel(p3_11, mD, vD), &out[base3 + WC4 + C4]);
}

extern "C" void kernel_launch(void* const* d_in, const int* in_sizes, int n_in,
                              void* d_out, int out_size, void* d_ws, size_t ws_size,
                              hipStream_t stream) {
    const v4* input = (const v4*)d_in[0];
    const v4* pool  = (const v4*)d_in[1];
    v4* out = (v4*)d_out;

    const int block = 256;
    const int grid = QN / block;   // 2048 blocks
    unpool2d_kernel<<<grid, block, 0, stream>>>(input, pool, out);
}